// Round 1
// baseline (102.503 us; speedup 1.0000x reference)
//
#include <hip/hip_runtime.h>
#include <hip/hip_bf16.h>

#define HH 8
#define SEQL 4096
#define DD 128
#define NBLK 64
#define LOCAL_B 16

typedef __attribute__((ext_vector_type(8))) short bf16x8;
typedef __attribute__((ext_vector_type(4))) float f32x4;

// LDS strides in elements (bf16). Padded to break power-of-2 bank patterns.
#define K_STR 136   // 64 x 136 x 2B = 17408
#define VT_STR 72   // 128 x 72 x 2B = 18432
#define P_STR 72    // 4 waves x 16 x 72 x 2B = 9216

__device__ __forceinline__ unsigned short f2bf(float x) {
    union { float f; unsigned u; } a; a.f = x;
    unsigned r = a.u + 0x7FFFu + ((a.u >> 16) & 1u);
    return (unsigned short)(r >> 16);
}

__global__ __launch_bounds__(256, 2)
void bsattn_kernel(const float* __restrict__ q, const float* __restrict__ k,
                   const float* __restrict__ v, const float* __restrict__ scl,
                   float* __restrict__ out) {
    const int h   = blockIdx.x & 7;
    const int qb  = (NBLK - 1) - (blockIdx.x >> 3);   // heavy query blocks first
    const int tid = threadIdx.x;
    const int w   = tid >> 6;      // wave 0..3
    const int l   = tid & 63;
    const int lr  = l & 15;        // lane % 16
    const int lg  = l >> 4;        // lane group 0..3

    __shared__ unsigned short lds_k[64 * K_STR];
    __shared__ unsigned short lds_vt[128 * VT_STR];
    __shared__ unsigned short lds_p[4 * 16 * P_STR];

    const float kappa = scl[0] * 1.44269504088896f;  // sm_scale * log2(e)

    const size_t hb = (size_t)h * SEQL * DD;
    const float* qh = q + hb;
    const float* kh = k + hb;
    const float* vh = v + hb;
    float* oh = out + hb;

    // ---- Q -> register fragments (wave w owns q rows 16w .. 16w+15) ----
    bf16x8 qf[4];
    {
        const float* qrow = qh + (size_t)(qb * 64 + 16 * w + lr) * DD;
        for (int ks = 0; ks < 4; ++ks) {
            const float4* p4 = (const float4*)(qrow + ks * 32 + lg * 8);
            float4 x = p4[0], y = p4[1];
            union { bf16x8 v8; unsigned short u[8]; } pk;
            pk.u[0] = f2bf(x.x); pk.u[1] = f2bf(x.y);
            pk.u[2] = f2bf(x.z); pk.u[3] = f2bf(x.w);
            pk.u[4] = f2bf(y.x); pk.u[5] = f2bf(y.y);
            pk.u[6] = f2bf(y.z); pk.u[7] = f2bf(y.w);
            qf[ks] = pk.v8;
        }
    }

    f32x4 oacc[8];
    for (int i = 0; i < 8; ++i) oacc[i] = (f32x4){0.f, 0.f, 0.f, 0.f};
    float mrun[4], lrun[4];
    for (int j = 0; j < 4; ++j) { mrun[j] = -1e30f; lrun[j] = 0.f; }

    auto process = [&](int kb, bool diag) {
        __syncthreads();   // previous iteration's LDS reads must be done
        // ---- stage K block: [64][128] f32 -> bf16 LDS [64][K_STR] ----
        {
            const float* kp = kh + (size_t)kb * 64 * DD;
            #pragma unroll
            for (int i = 0; i < 4; ++i) {
                int c = i * 256 + tid;          // 1024 chunks of 8 elems
                int row = c >> 4, cc = c & 15;
                const float4* s4 = (const float4*)(kp + row * DD + cc * 8);
                float4 x = s4[0], y = s4[1];
                union { bf16x8 v8; unsigned short u[8]; } pk;
                pk.u[0] = f2bf(x.x); pk.u[1] = f2bf(x.y);
                pk.u[2] = f2bf(x.z); pk.u[3] = f2bf(x.w);
                pk.u[4] = f2bf(y.x); pk.u[5] = f2bf(y.y);
                pk.u[6] = f2bf(y.z); pk.u[7] = f2bf(y.w);
                *(bf16x8*)&lds_k[row * K_STR + cc * 8] = pk.v8;
            }
        }
        // ---- stage V transposed: Vt[d][token], bf16 LDS [128][VT_STR] ----
        {
            const float* vp = vh + (size_t)kb * 64 * DD;
            int c  = tid & 127;     // d column
            int rg = tid >> 7;      // row-group 0/1 (rows 32 each)
            #pragma unroll
            for (int i = 0; i < 4; ++i) {
                union { bf16x8 v8; unsigned short u[8]; } pk;
                #pragma unroll
                for (int r = 0; r < 8; ++r)
                    pk.u[r] = f2bf(vp[(rg * 32 + i * 8 + r) * DD + c]);
                *(bf16x8*)&lds_vt[c * VT_STR + rg * 32 + i * 8] = pk.v8;
            }
        }
        __syncthreads();

        // ---- S = Q K^T  (wave: 16 rows x 64 cols, 4 col-tiles) ----
        f32x4 sacc[4];
        for (int ct = 0; ct < 4; ++ct) sacc[ct] = (f32x4){0.f, 0.f, 0.f, 0.f};
        #pragma unroll
        for (int ks = 0; ks < 4; ++ks) {
            #pragma unroll
            for (int ct = 0; ct < 4; ++ct) {
                bf16x8 kf = *(const bf16x8*)&lds_k[(ct * 16 + lr) * K_STR + ks * 32 + lg * 8];
                sacc[ct] = __builtin_amdgcn_mfma_f32_16x16x32_bf16(qf[ks], kf, sacc[ct], 0, 0, 0);
            }
        }

        // ---- online softmax (exp2 domain) ----
        float pv[4][4];          // [ct][j]
        float mloc[4] = {-1e30f, -1e30f, -1e30f, -1e30f};
        #pragma unroll
        for (int ct = 0; ct < 4; ++ct)
            #pragma unroll
            for (int j = 0; j < 4; ++j) {
                float sv = sacc[ct][j] * kappa;
                if (diag) {
                    int rowt = 16 * w + 4 * lg + j;
                    int colt = ct * 16 + lr;
                    if (colt > rowt) sv = -1e30f;
                }
                pv[ct][j] = sv;
                mloc[j] = fmaxf(mloc[j], sv);
            }
        #pragma unroll
        for (int off = 1; off < 16; off <<= 1)
            #pragma unroll
            for (int j = 0; j < 4; ++j)
                mloc[j] = fmaxf(mloc[j], __shfl_xor(mloc[j], off));
        float sf[4];
        #pragma unroll
        for (int j = 0; j < 4; ++j) {
            float mn = fmaxf(mrun[j], mloc[j]);
            sf[j] = exp2f(mrun[j] - mn);
            mrun[j] = mn;
        }
        float rowsum[4] = {0.f, 0.f, 0.f, 0.f};
        #pragma unroll
        for (int ct = 0; ct < 4; ++ct)
            #pragma unroll
            for (int j = 0; j < 4; ++j) {
                float p = exp2f(pv[ct][j] - mrun[j]);
                pv[ct][j] = p;
                rowsum[j] += p;
            }
        #pragma unroll
        for (int j = 0; j < 4; ++j) lrun[j] = lrun[j] * sf[j] + rowsum[j];
        #pragma unroll
        for (int dt = 0; dt < 8; ++dt) {
            f32x4 o = oacc[dt];
            o[0] *= sf[0]; o[1] *= sf[1]; o[2] *= sf[2]; o[3] *= sf[3];
            oacc[dt] = o;
        }

        // ---- P -> LDS (D-layout) then re-read in A-layout ----
        unsigned short* pw = &lds_p[w * 16 * P_STR];
        #pragma unroll
        for (int ct = 0; ct < 4; ++ct)
            #pragma unroll
            for (int j = 0; j < 4; ++j)
                pw[(4 * lg + j) * P_STR + ct * 16 + lr] = f2bf(pv[ct][j]);
        __syncthreads();
        bf16x8 pf[2];
        #pragma unroll
        for (int ks = 0; ks < 2; ++ks)
            pf[ks] = *(const bf16x8*)&pw[lr * P_STR + ks * 32 + lg * 8];
        // ---- O += P V ----
        #pragma unroll
        for (int ks = 0; ks < 2; ++ks)
            #pragma unroll
            for (int dt = 0; dt < 8; ++dt) {
                bf16x8 vf = *(const bf16x8*)&lds_vt[(dt * 16 + lr) * VT_STR + ks * 32 + lg * 8];
                oacc[dt] = __builtin_amdgcn_mfma_f32_16x16x32_bf16(pf[ks], vf, oacc[dt], 0, 0, 0);
            }
    };

    // ---- iterate active k blocks: vertical-strided tail, then local band ----
    {
        int vstart = (7 - h) & 7;                 // kb with (kb + h + 1) % 8 == 0
        for (int kb = vstart; kb <= qb - LOCAL_B; kb += 8) process(kb, false);
        int lo = qb - (LOCAL_B - 1); if (lo < 0) lo = 0;
        for (int kb = lo; kb < qb; ++kb) process(kb, false);
        process(qb, true);                        // diagonal block, causal-masked
    }

    // ---- epilogue: finish row sums, normalize, write out ----
    float rcp[4];
    #pragma unroll
    for (int j = 0; j < 4; ++j) {
        float s = lrun[j];
        #pragma unroll
        for (int off = 1; off < 16; off <<= 1) s += __shfl_xor(s, off);
        rcp[j] = 1.0f / s;
    }
    float* orow = oh + (size_t)(qb * 64 + 16 * w) * DD;
    #pragma unroll
    for (int dt = 0; dt < 8; ++dt)
        #pragma unroll
        for (int j = 0; j < 4; ++j)
            orow[(4 * lg + j) * DD + dt * 16 + lr] = oacc[dt][j] * rcp[j];
}

extern "C" void kernel_launch(void* const* d_in, const int* in_sizes, int n_in,
                              void* d_out, int out_size, void* d_ws, size_t ws_size,
                              hipStream_t stream) {
    const float* q   = (const float*)d_in[0];
    const float* k   = (const float*)d_in[1];
    const float* v   = (const float*)d_in[2];
    const float* scl = (const float*)d_in[3];
    float* out = (float*)d_out;

    dim3 grid(HH * NBLK);
    dim3 block(256);
    bsattn_kernel<<<grid, block, 0, stream>>>(q, k, v, scl, out);
}

// Round 2
// 69.262 us; speedup vs baseline: 1.4799x; 1.4799x over previous
//
#include <hip/hip_runtime.h>
#include <hip/hip_bf16.h>

#define HH 8
#define SEQL 4096
#define DD 128
#define NBLK 64
#define LOCAL_B 16
#define P_STR 72

typedef __attribute__((ext_vector_type(8))) short bf16x8;
typedef __attribute__((ext_vector_type(4))) float f32x4;
typedef unsigned short ushort_t;

typedef const __attribute__((address_space(1))) unsigned int gu32;
typedef __attribute__((address_space(3))) unsigned int lu32;

__device__ __forceinline__ unsigned short f2bf(float x) {
    union { float f; unsigned u; } a; a.f = x;
    unsigned r = a.u + 0x7FFFu + ((a.u >> 16) & 1u);
    return (unsigned short)(r >> 16);
}

__device__ __forceinline__ void gload16(const void* src, void* ldsdst) {
    __builtin_amdgcn_global_load_lds((gu32*)src, (lu32*)ldsdst, 16, 0, 0);
}

// ---------------- prepass: K f32 -> bf16 flat ----------------
__global__ void convert_k(const float* __restrict__ k, ushort_t* __restrict__ kb) {
    int idx = (blockIdx.x * 256 + threadIdx.x) * 8;
    const float4* s = (const float4*)(k + idx);
    float4 a = s[0], b = s[1];
    union { bf16x8 v8; ushort_t u[8]; } p;
    p.u[0] = f2bf(a.x); p.u[1] = f2bf(a.y); p.u[2] = f2bf(a.z); p.u[3] = f2bf(a.w);
    p.u[4] = f2bf(b.x); p.u[5] = f2bf(b.y); p.u[6] = f2bf(b.z); p.u[7] = f2bf(b.w);
    *(bf16x8*)(kb + idx) = p.v8;
}

// ---------------- prepass: V f32 [H][S][D] -> bf16 Vt [H][D][S] ----------------
#define T_STR 136
__global__ void transpose_v(const float* __restrict__ v, ushort_t* __restrict__ vt) {
    __shared__ ushort_t t[64 * T_STR];
    int h  = blockIdx.x >> 6;
    int sb = blockIdx.x & 63;
    const float* vp = v + ((size_t)h * SEQL + sb * 64) * DD;
    int tid = threadIdx.x;
    {
        int col = (tid & 15) * 8;
        #pragma unroll
        for (int it = 0; it < 4; ++it) {
            int row = it * 16 + (tid >> 4);
            const float4* s = (const float4*)(vp + row * DD + col);
            float4 a = s[0], b = s[1];
            union { bf16x8 v8; ushort_t u[8]; } p;
            p.u[0] = f2bf(a.x); p.u[1] = f2bf(a.y); p.u[2] = f2bf(a.z); p.u[3] = f2bf(a.w);
            p.u[4] = f2bf(b.x); p.u[5] = f2bf(b.y); p.u[6] = f2bf(b.z); p.u[7] = f2bf(b.w);
            *(bf16x8*)&t[row * T_STR + col] = p.v8;
        }
    }
    __syncthreads();
    {
        int d = tid >> 1, seg = tid & 1;
        ushort_t* dst = vt + ((size_t)h * DD + d) * SEQL + sb * 64 + seg * 32;
        #pragma unroll
        for (int i = 0; i < 4; ++i) {
            union { bf16x8 v8; ushort_t u[8]; } o;
            #pragma unroll
            for (int e = 0; e < 8; ++e)
                o.u[e] = t[(seg * 32 + i * 8 + e) * T_STR + d];
            *(bf16x8*)(dst + i * 8) = o.v8;
        }
    }
}

// ---------------- main attention kernel ----------------
__global__ __launch_bounds__(256, 2)
void bsattn2(const float* __restrict__ q, const ushort_t* __restrict__ kbuf,
             const ushort_t* __restrict__ vtbuf, const float* __restrict__ scl,
             float* __restrict__ out) {
    const int g  = blockIdx.x;
    const int h  = g & 7;
    const int i0 = g >> 3;
    const int qb = (i0 < 32) ? (63 - i0) : (i0 - 32);   // pair heavy with light
    const int tid = threadIdx.x;
    const int w  = tid >> 6;
    const int l  = tid & 63;
    const int lr = l & 15;
    const int lg = l >> 4;

    __shared__ ushort_t lds_k[2][64 * 128];
    __shared__ ushort_t lds_v[2][128 * 64];
    __shared__ ushort_t lds_p[4][16 * P_STR];

    const float kappa = scl[0] * 1.44269504088896f;

    const float*    qh = q     + (size_t)h * SEQL * DD;
    const ushort_t* kh = kbuf  + (size_t)h * SEQL * DD;
    const ushort_t* vh = vtbuf + (size_t)h * DD * SEQL;
    float*          oh = out   + (size_t)h * SEQL * DD;

    // Q -> register fragments (wave w owns q rows 16w..16w+15)
    bf16x8 qf[4];
    {
        const float* qrow = qh + (size_t)(qb * 64 + 16 * w + lr) * DD;
        #pragma unroll
        for (int ks = 0; ks < 4; ++ks) {
            const float4* p4 = (const float4*)(qrow + ks * 32 + lg * 8);
            float4 x = p4[0], y = p4[1];
            union { bf16x8 v8; ushort_t u[8]; } pk;
            pk.u[0] = f2bf(x.x); pk.u[1] = f2bf(x.y);
            pk.u[2] = f2bf(x.z); pk.u[3] = f2bf(x.w);
            pk.u[4] = f2bf(y.x); pk.u[5] = f2bf(y.y);
            pk.u[6] = f2bf(y.z); pk.u[7] = f2bf(y.w);
            qf[ks] = pk.v8;
        }
    }

    f32x4 oacc[8];
    #pragma unroll
    for (int i = 0; i < 8; ++i) oacc[i] = (f32x4){0.f, 0.f, 0.f, 0.f};
    float mrun[4], lrun[4];
    #pragma unroll
    for (int j = 0; j < 4; ++j) { mrun[j] = -1e30f; lrun[j] = 0.f; }

    auto stage = [&](int buf, int kb) {
        const char* kbase = (const char*)(kh + (size_t)kb * 64 * DD);
        #pragma unroll
        for (int j = 0; j < 4; ++j) {
            int row  = w * 16 + j * 4 + (l >> 4);
            int colb = ((l & 15) << 4) ^ ((row & 7) << 4);
            gload16(kbase + row * 256 + colb, &lds_k[buf][(w * 16 + j * 4) * 128]);
        }
        const char* vbase = (const char*)vh + (size_t)kb * 128;  // + d*8192
        #pragma unroll
        for (int j = 0; j < 4; ++j) {
            int d0 = w * 32 + j * 8;
            int d  = d0 + (l >> 3);
            int colb = ((l & 7) << 4) ^ ((d & 7) << 4);
            gload16(vbase + (size_t)d * (SEQL * 2) + colb, &lds_v[buf][d0 * 64]);
        }
    };

    auto compute = [&](int buf, bool diag) {
        const char* kb8 = (const char*)&lds_k[buf][0];
        f32x4 sacc[4];
        #pragma unroll
        for (int ct = 0; ct < 4; ++ct) sacc[ct] = (f32x4){0.f, 0.f, 0.f, 0.f};
        #pragma unroll
        for (int ks = 0; ks < 4; ++ks) {
            #pragma unroll
            for (int ct = 0; ct < 4; ++ct) {
                int row = ct * 16 + lr;
                bf16x8 kf = *(const bf16x8*)(kb8 + row * 256 +
                                             ((ks * 64 + lg * 16) ^ ((row & 7) << 4)));
                sacc[ct] = __builtin_amdgcn_mfma_f32_16x16x32_bf16(qf[ks], kf, sacc[ct], 0, 0, 0);
            }
        }

        // online softmax (exp2 domain)
        float pv[4][4];
        float mloc[4] = {-1e30f, -1e30f, -1e30f, -1e30f};
        #pragma unroll
        for (int ct = 0; ct < 4; ++ct)
            #pragma unroll
            for (int j = 0; j < 4; ++j) {
                float sv = sacc[ct][j] * kappa;
                if (diag) {
                    int rowt = 16 * w + 4 * lg + j;
                    int colt = ct * 16 + lr;
                    if (colt > rowt) sv = -1e30f;
                }
                pv[ct][j] = sv;
                mloc[j] = fmaxf(mloc[j], sv);
            }
        #pragma unroll
        for (int off = 1; off < 16; off <<= 1)
            #pragma unroll
            for (int j = 0; j < 4; ++j)
                mloc[j] = fmaxf(mloc[j], __shfl_xor(mloc[j], off));
        float sf[4];
        #pragma unroll
        for (int j = 0; j < 4; ++j) {
            float mn = fmaxf(mrun[j], mloc[j]);
            sf[j] = exp2f(mrun[j] - mn);
            mrun[j] = mn;
        }
        float rowsum[4] = {0.f, 0.f, 0.f, 0.f};
        #pragma unroll
        for (int ct = 0; ct < 4; ++ct)
            #pragma unroll
            for (int j = 0; j < 4; ++j) {
                float p = exp2f(pv[ct][j] - mrun[j]);
                pv[ct][j] = p;
                rowsum[j] += p;
            }
        #pragma unroll
        for (int j = 0; j < 4; ++j) lrun[j] = lrun[j] * sf[j] + rowsum[j];
        #pragma unroll
        for (int dt = 0; dt < 8; ++dt) {
            f32x4 o = oacc[dt];
            o[0] *= sf[0]; o[1] *= sf[1]; o[2] *= sf[2]; o[3] *= sf[3];
            oacc[dt] = o;
        }

        // P -> per-wave LDS (no cross-wave barrier needed)
        ushort_t* pw = &lds_p[w][0];
        #pragma unroll
        for (int ct = 0; ct < 4; ++ct)
            #pragma unroll
            for (int j = 0; j < 4; ++j)
                pw[(4 * lg + j) * P_STR + ct * 16 + lr] = f2bf(pv[ct][j]);
        asm volatile("s_waitcnt lgkmcnt(0)" ::: "memory");
        __builtin_amdgcn_sched_barrier(0);
        bf16x8 pf[2];
        #pragma unroll
        for (int ks = 0; ks < 2; ++ks)
            pf[ks] = *(const bf16x8*)&pw[lr * P_STR + ks * 32 + lg * 8];

        const char* vb8 = (const char*)&lds_v[buf][0];
        #pragma unroll
        for (int ks = 0; ks < 2; ++ks)
            #pragma unroll
            for (int dt = 0; dt < 8; ++dt) {
                int row = dt * 16 + lr;
                bf16x8 vf = *(const bf16x8*)(vb8 + row * 128 +
                                             ((ks * 64 + lg * 16) ^ ((row & 7) << 4)));
                oacc[dt] = __builtin_amdgcn_mfma_f32_16x16x32_bf16(pf[ks], vf, oacc[dt], 0, 0, 0);
            }
    };

    // active-kb iteration: vertical-strided tail, then local band, then diagonal
    const int vstart = (7 - h) & 7;
    int lo = qb - (LOCAL_B - 1); if (lo < 0) lo = 0;
    int kb = (vstart <= qb - LOCAL_B) ? vstart : lo;
    int cur = 0;
    stage(0, kb);
    while (kb >= 0) {
        int kn;
        if (kb < lo) { int n = kb + 8; kn = (n <= qb - LOCAL_B) ? n : lo; }
        else if (kb < qb) kn = kb + 1;
        else kn = -1;

        if (kn >= 0) {
            stage(cur ^ 1, kn);
            asm volatile("s_waitcnt vmcnt(8)" ::: "memory");
        } else {
            asm volatile("s_waitcnt vmcnt(0)" ::: "memory");
        }
        __builtin_amdgcn_sched_barrier(0);
        __builtin_amdgcn_s_barrier();
        __builtin_amdgcn_sched_barrier(0);

        compute(cur, kb == qb);

        __builtin_amdgcn_s_barrier();
        cur ^= 1;
        kb = kn;
    }

    // epilogue
    float rcp[4];
    #pragma unroll
    for (int j = 0; j < 4; ++j) {
        float s = lrun[j];
        #pragma unroll
        for (int off = 1; off < 16; off <<= 1) s += __shfl_xor(s, off);
        rcp[j] = 1.0f / s;
    }
    float* orow = oh + (size_t)(qb * 64 + 16 * w) * DD;
    #pragma unroll
    for (int dt = 0; dt < 8; ++dt)
        #pragma unroll
        for (int j = 0; j < 4; ++j)
            orow[(4 * lg + j) * DD + dt * 16 + lr] = oacc[dt][j] * rcp[j];
}

extern "C" void kernel_launch(void* const* d_in, const int* in_sizes, int n_in,
                              void* d_out, int out_size, void* d_ws, size_t ws_size,
                              hipStream_t stream) {
    const float* q   = (const float*)d_in[0];
    const float* k   = (const float*)d_in[1];
    const float* v   = (const float*)d_in[2];
    const float* scl = (const float*)d_in[3];
    float* out = (float*)d_out;

    ushort_t* Kb = (ushort_t*)d_ws;                          // 8 MB bf16 K
    ushort_t* Vt = Kb + (size_t)HH * SEQL * DD;              // 8 MB bf16 V^T

    convert_k<<<dim3((HH * SEQL * DD) / (256 * 8)), dim3(256), 0, stream>>>(k, Kb);
    transpose_v<<<dim3(HH * 64), dim3(256), 0, stream>>>(v, Vt);
    bsattn2<<<dim3(HH * NBLK), dim3(256), 0, stream>>>(q, Kb, Vt, scl, out);
}